// Round 10
// baseline (156.020 us; speedup 1.0000x reference)
//
#include <hip/hip_runtime.h>
#include <hip/hip_bf16.h>
#include <stdint.h>

#define AS1 __attribute__((address_space(1)))
#define AS3 __attribute__((address_space(3)))

typedef __bf16 bf16x8 __attribute__((ext_vector_type(8)));
typedef float  f32x4  __attribute__((ext_vector_type(4)));
typedef unsigned short ushort8v __attribute__((ext_vector_type(8)));
typedef unsigned short ushort4v __attribute__((ext_vector_type(4)));
typedef short short8v __attribute__((ext_vector_type(8)));
typedef short short4v __attribute__((ext_vector_type(4)));

__device__ __forceinline__ unsigned short f2bf(float f) {
    unsigned int u = __float_as_uint(f);
    u += 0x7fffu + ((u >> 16) & 1u);           // round-to-nearest-even
    return (unsigned short)(u >> 16);
}
__device__ __forceinline__ unsigned int pk2bf(float a, float b) {
    __hip_bfloat162 h = __float22bfloat162_rn(make_float2(a, b));  // x->low short
    unsigned int u;
    __builtin_memcpy(&u, &h, 4);
    return u;
}
__device__ __forceinline__ void g2lds16(const void* gp, void* lp) {
    __builtin_amdgcn_global_load_lds((AS1 void*)gp, (AS3 void*)lp, 16, 0, 0);
}
#define E2(x) __builtin_amdgcn_exp2f(x)

// ---------------- cast fp32 -> bf16 (x, Wq, Wk, Wv in one launch) -----------
__global__ __launch_bounds__(256) void cast_all(const float* __restrict__ x,
                                                const float* __restrict__ w0,
                                                const float* __restrict__ w1,
                                                const float* __restrict__ w2,
                                                unsigned short* __restrict__ xb,
                                                unsigned short* __restrict__ wc) {
    int id = blockIdx.x;
    const float* s;
    unsigned short* d;
    int base;
    if (id < 4096) { s = x; d = xb; base = id; }
    else {
        int z = (id - 4096) >> 10;
        s = (z == 0) ? w0 : (z == 1) ? w1 : w2;
        d = wc + (size_t)z * 1048576;
        base = (id - 4096) & 1023;
    }
    int i = (base * 256 + threadIdx.x) * 4;
    float4 v = *(const float4*)(s + i);
    ushort4v o = { f2bf(v.x), f2bf(v.y), f2bf(v.z), f2bf(v.w) };
    *(ushort4v*)(d + i) = o;
}

// ---------------- QKV GEMM: R18 256^2 8-phase, fixed swizzle + B-carry ------
// (unchanged from R18 — measured: gemm < 43us, conflicts fixed)
#define VMW(n) asm volatile("s_waitcnt vmcnt(" #n ")" ::: "memory")
#define NOW
#define PHCORE(STG, MFMAS, ENDW) do {                                          \
    STG;                                                                       \
    __builtin_amdgcn_s_barrier();                                              \
    asm volatile("s_waitcnt lgkmcnt(0)" ::: "memory");                         \
    __builtin_amdgcn_sched_barrier(0);                                         \
    __builtin_amdgcn_s_setprio(1);                                             \
    MFMAS;                                                                     \
    __builtin_amdgcn_s_setprio(0);                                             \
    __builtin_amdgcn_sched_barrier(0);                                         \
    ENDW;                                                                      \
    __builtin_amdgcn_s_barrier();                                              \
} while (0)

#define PHA(S, CUR, STG, ENDW) do {                                            \
    const int kx_ = ((S) * 32 + quad * 8) ^ ((cl & 7) * 8);                    \
    bf16x8 af_[4];                                                             \
    _Pragma("unroll")                                                          \
    for (int m_ = 0; m_ < 4; ++m_)                                             \
        af_[m_] = *(const bf16x8*)&SA[CUR][(rowA0 + m_ * 16) * 64 + kx_];      \
    _Pragma("unroll")                                                          \
    for (int n_ = 0; n_ < 4; ++n_)                                             \
        bqr[n_] = *(const bf16x8*)&SB[CUR][(rowB0 + n_ * 16) * 64 + kx_];      \
    PHCORE(STG,                                                                \
        _Pragma("unroll")                                                      \
        for (int m_ = 0; m_ < 4; ++m_)                                         \
            _Pragma("unroll")                                                  \
            for (int n_ = 0; n_ < 4; ++n_)                                     \
                acc[m_][n_] = __builtin_amdgcn_mfma_f32_16x16x32_bf16(         \
                    af_[m_], bqr[n_], acc[m_][n_], 0, 0, 0);                   \
        , ENDW);                                                               \
} while (0)

#define PHB(S, CUR, STG, ENDW) do {                                            \
    const int kx_ = ((S) * 32 + quad * 8) ^ ((cl & 7) * 8);                    \
    bf16x8 af_[4];                                                             \
    _Pragma("unroll")                                                          \
    for (int m_ = 0; m_ < 4; ++m_)                                             \
        af_[m_] = *(const bf16x8*)&SA[CUR][(rowA0 + 64 + m_ * 16) * 64 + kx_]; \
    PHCORE(STG,                                                                \
        _Pragma("unroll")                                                      \
        for (int m_ = 0; m_ < 4; ++m_)                                         \
            _Pragma("unroll")                                                  \
            for (int n_ = 0; n_ < 4; ++n_)                                     \
                acc[4 + m_][n_] = __builtin_amdgcn_mfma_f32_16x16x32_bf16(     \
                    af_[m_], bqr[n_], acc[4 + m_][n_], 0, 0, 0);               \
        , ENDW);                                                               \
} while (0)

__global__ __launch_bounds__(512, 2) void gemm_qkv(const unsigned short* __restrict__ X,
                                                   const unsigned short* __restrict__ W,
                                                   unsigned short* __restrict__ QKV) {
    const int K = 1024, N = 1024;
    const int b = blockIdx.x;                  // 192 blocks
    const int z = b >> 6;                      // 0..2
    const int r = b & 63;
    const int m0 = (r >> 2) * 256;             // 16 m-tiles
    const int n0 = (r & 3) * 256;              // 4 n-tiles

    const unsigned short* A = X;
    const unsigned short* Bp = W + (size_t)z * (1024 * 1024);
    unsigned short* C = QKV + (size_t)z * (4096 * 1024);
    const float qs = (z == 0) ? 0.18033688011112042f : 1.0f;

    __shared__ unsigned short SA[2][16384];    // [buf][256 rows x 64 k]
    __shared__ unsigned short SB[2][16384];

    const int t = threadIdx.x;                 // 0..511
    const int w = t >> 6;
    const int l = t & 63;
    const int cl = l & 15;
    const int quad = l >> 4;
    const int rowA0 = (w >> 2) * 128 + cl;
    const int rowB0 = (w & 3) * 64 + cl;

    const int srow8 = t >> 3;                  // row within quarter 0..63
    const int klog = (((t & 7) ^ ((t >> 3) & 7)) * 8);
    const unsigned short* Abase = A + (size_t)(m0 + srow8) * K + klog;
    const unsigned short* Bbase = Bp + (size_t)(n0 + srow8) * K + klog;
    unsigned short* const sa0 = &SA[0][w * 512];
    unsigned short* const sa1 = &SA[1][w * 512];
    unsigned short* const sb0 = &SB[0][w * 512];
    unsigned short* const sb1 = &SB[1][w * 512];

    f32x4 acc[8][4] = {};
    bf16x8 bqr[4];

#define STGA(nb, q, k0) g2lds16(Abase + (size_t)(q) * 65536 + (k0), ((nb) ? sa1 : sa0) + (q) * 4096)
#define STGB(nb, q, k0) g2lds16(Bbase + (size_t)(q) * 65536 + (k0), ((nb) ? sb1 : sb0) + (q) * 4096)

    STGB(0, 0, 0); STGB(0, 1, 0); STGB(0, 2, 0); STGB(0, 3, 0);
    STGA(0, 0, 0); STGA(0, 2, 0); STGA(0, 1, 0); STGA(0, 3, 0);
    VMW(2);
    __builtin_amdgcn_s_barrier();

    for (int tt = 0; tt < 15; ++tt) {
        const int cur = tt & 1, nxt = cur ^ 1;
        const int k1 = (tt + 1) * 64;
        PHA(0, cur, { STGB(nxt, 0, k1); STGB(nxt, 1, k1); }, VMW(2));
        PHB(0, cur, { STGB(nxt, 2, k1); STGB(nxt, 3, k1); }, NOW);
        PHA(1, cur, { STGA(nxt, 0, k1); STGA(nxt, 2, k1); }, NOW);
        PHB(1, cur, { STGA(nxt, 1, k1); STGA(nxt, 3, k1); }, VMW(2));
    }
    PHA(0, 1, {}, VMW(0));
    PHB(0, 1, {}, NOW);
    PHA(1, 1, {}, NOW);
    PHB(1, 1, {}, NOW);

#undef STGA
#undef STGB

    #pragma unroll
    for (int mf = 0; mf < 8; ++mf) {
        #pragma unroll
        for (int rr = 0; rr < 4; ++rr) {
            size_t row = (size_t)(m0 + (w >> 2) * 128 + mf * 16 + quad * 4 + rr);
            #pragma unroll
            for (int nf = 0; nf < 4; ++nf)
                C[row * N + (n0 + (w & 3) * 64 + nf * 16 + cl)] = f2bf(acc[mf][nf][rr] * qs);
        }
    }
}

// ---------------- V swizzle to VT3 (per bh) ---------------------------------
__global__ __launch_bounds__(256) void vtrans(const unsigned short* __restrict__ Vn,
                                              unsigned short* __restrict__ V3) {
    const int bh = blockIdx.y;
    const int T0 = blockIdx.x * 128;
    __shared__ unsigned short L[128 * 72];
    const int t = threadIdx.x;

    const unsigned short* src = Vn + (size_t)bh * 131072 + (size_t)T0 * 64;
    #pragma unroll
    for (int p = 0; p < 4; ++p) {
        int r = p * 32 + (t >> 3), c = (t & 7) * 8;
        *(ushort8v*)(L + r * 72 + c) = *(const ushort8v*)(src + (size_t)r * 64 + c);
    }
    __syncthreads();
    unsigned short* dst = V3 + (size_t)bh * 131072 + (size_t)(T0 >> 4) * 1024;
    #pragma unroll
    for (int p = 0; p < 2; ++p) {
        int item = p * 256 + t;                 // 512 items: kb(8) x cl(16) x qk(4)
        int kb = item >> 6, cl = (item >> 2) & 15, qk = item & 3;
        ushort8v a, b;
        #pragma unroll
        for (int u = 0; u < 8; ++u) {
            int dt = u >> 2, j = u & 3;
            a[u] = L[(kb * 16 + qk * 4 + j) * 72 + dt * 16 + cl];
            b[u] = L[(kb * 16 + qk * 4 + j) * 72 + (dt + 2) * 16 + cl];
        }
        unsigned short* dp = dst + kb * 1024 + cl * 64 + qk * 16;
        *(ushort8v*)(dp) = a;
        *(ushort8v*)(dp + 8) = b;
    }
}

// ---------------- Flash attention: R19 q=32/wave LDS amortization -----------
// Budget model (R15-R18 fits): attn ~43us. Pipe arithmetic: MFMA floor 21.6us
// (QK 7.2 + PV-_1k 14.4), LDS-read ~21us (16 b128/wave-chunk for only 16 q).
// R19: 2-wave 128-thread blocks, 32 q-rows/wave (same 64-row band, same 1024
// grid, same bb/nch/heavy-first/bh maps). K frags loaded once per chunk and V
// frags once per kt serve BOTH q-blocks -> LDS-read bytes per output HALVED
// (~21 -> ~11us). 4 blocks/CU (32KB LDS, VGPR<=256 via bounds(128,2)) = 2
// waves/SIMD with 4 independent barrier domains. Staging: per-thread 4 K + 4
// V granules; derived identity: granule g=(i*128+t) sits at LDS offset g*8,
// src offset = base + i*1024 (same swizzle formulas, t in 0..127).
__global__ __launch_bounds__(128, 2) void attn(const unsigned short* __restrict__ QK,
                                               const unsigned short* __restrict__ V3,
                                               float* __restrict__ Out) {
    const int id = blockIdx.x;                         // 1024 blocks
    const int bh = id & 31;                            // 4 bh per XCD (id%8 = XCD)
    const int bb = 31 - (id >> 5);                     // 64-row band, heavy-first
    const int t = threadIdx.x;                         // 0..127
    const int w = t >> 6;                              // wave 0..1
    const int l = t & 63;
    const int cl = l & 15;
    const int quad = l >> 4;
    const int c7 = cl & 7;

    const size_t bhoff = (size_t)bh * 131072;
    const unsigned short* Qb = QK + bhoff;
    const unsigned short* Kb = QK + (size_t)4194304 + bhoff;
    const unsigned short* Vb = V3 + bhoff;
    float* Ob = Out + bhoff;

    __shared__ unsigned short KVs[2][8192];            // per buf: K 4096 | V 4096

    // staging bases (t in 0..127); group i source/dest offset = +i*1024
    const int kOb = (t >> 3) * 64 + (((t & 7) ^ ((t >> 3) & 7)) * 8);
    const int vOb = (t >> 6) * 512 + (((t & 63) ^ ((t >> 3) & 7)) * 8);
    const int lB = w * 512;                            // shorts (wave-uniform)

    // read offsets (R9-verified, lane-local, unchanged)
    const int oK0 = cl * 64 + (((quad)     ^ c7) * 8);
    const int oK1 = cl * 64 + (((quad + 4) ^ c7) * 8);
    const int oV0 = cl * 64 + (((quad * 2)     ^ c7) * 8);
    const int oV1 = cl * 64 + (((quad * 2 + 1) ^ c7) * 8);

    const int nch = bb + 1;                            // chunks for this band
    const int m0w = bb * 64 + w * 32;                  // wave's first q-row
    const int mrel0 = w * 32 + cl;                     // diag row rel. chunk base
    const int mrel1 = w * 32 + 16 + cl;

    bf16x8 qf[2][2];
    #pragma unroll
    for (int qb = 0; qb < 2; ++qb) {
        const unsigned short* qa = Qb + (size_t)(m0w + qb * 16 + cl) * 64 + quad * 8;
        qf[qb][0] = *(const bf16x8*)(qa);
        qf[qb][1] = *(const bf16x8*)(qa + 32);
    }

    f32x4 o0[4] = {}, o1[4] = {};
    float lps0 = 0.f, lps1 = 0.f;

    // stage chunk 0 into buf 0
    {
        unsigned short* s = &KVs[0][0];
        #pragma unroll
        for (int i = 0; i < 4; ++i) {
            g2lds16(Kb + i * 1024 + kOb, s + lB + i * 1024);
            g2lds16(Vb + i * 1024 + vOb, s + 4096 + lB + i * 1024);
        }
    }

    for (int c = 0; c < nch; ++c) {
        __syncthreads();                               // buf[c&1] ready
        if (c + 1 < nch) {
            unsigned short* s = &KVs[(c + 1) & 1][0];
            const size_t off = (size_t)(c + 1) * 4096;
            #pragma unroll
            for (int i = 0; i < 4; ++i) {
                g2lds16(Kb + off + i * 1024 + kOb, s + lB + i * 1024);
                g2lds16(Vb + off + i * 1024 + vOb, s + 4096 + lB + i * 1024);
            }
        }
        const unsigned short* Kl = &KVs[c & 1][0];
        const unsigned short* Vl = Kl + 4096;
        const bool masked = (c == bb);

        bf16x8 kf0[4], kf1[4];
        #pragma unroll
        for (int kt = 0; kt < 4; ++kt) {
            kf0[kt] = *(const bf16x8*)(Kl + kt * 1024 + oK0);
            kf1[kt] = *(const bf16x8*)(Kl + kt * 1024 + oK1);
        }
        f32x4 s0[4] = {}, s1[4] = {};
        __builtin_amdgcn_s_setprio(1);
        #pragma unroll
        for (int kt = 0; kt < 4; ++kt) {
            s0[kt] = __builtin_amdgcn_mfma_f32_16x16x32_bf16(kf0[kt], qf[0][0], s0[kt], 0, 0, 0);
            s0[kt] = __builtin_amdgcn_mfma_f32_16x16x32_bf16(kf1[kt], qf[0][1], s0[kt], 0, 0, 0);
            s1[kt] = __builtin_amdgcn_mfma_f32_16x16x32_bf16(kf0[kt], qf[1][0], s1[kt], 0, 0, 0);
            s1[kt] = __builtin_amdgcn_mfma_f32_16x16x32_bf16(kf1[kt], qf[1][1], s1[kt], 0, 0, 0);
        }
        __builtin_amdgcn_s_setprio(0);

        short4v pb0[4], pb1[4];
        #pragma unroll
        for (int kt = 0; kt < 4; ++kt) {
            const int lk = kt * 16 + quad * 4;
            float p0, p1, p2, p3;
            if (masked) {
                p0 = (lk     <= mrel0) ? E2(s0[kt][0]) : 0.f;
                p1 = (lk + 1 <= mrel0) ? E2(s0[kt][1]) : 0.f;
                p2 = (lk + 2 <= mrel0) ? E2(s0[kt][2]) : 0.f;
                p3 = (lk + 3 <= mrel0) ? E2(s0[kt][3]) : 0.f;
            } else {
                p0 = E2(s0[kt][0]); p1 = E2(s0[kt][1]);
                p2 = E2(s0[kt][2]); p3 = E2(s0[kt][3]);
            }
            lps0 += (p0 + p1) + (p2 + p3);
            uint2 u0 = { pk2bf(p0, p1), pk2bf(p2, p3) };
            __builtin_memcpy(&pb0[kt], &u0, 8);

            float r0, r1, r2, r3;
            if (masked) {
                r0 = (lk     <= mrel1) ? E2(s1[kt][0]) : 0.f;
                r1 = (lk + 1 <= mrel1) ? E2(s1[kt][1]) : 0.f;
                r2 = (lk + 2 <= mrel1) ? E2(s1[kt][2]) : 0.f;
                r3 = (lk + 3 <= mrel1) ? E2(s1[kt][3]) : 0.f;
            } else {
                r0 = E2(s1[kt][0]); r1 = E2(s1[kt][1]);
                r2 = E2(s1[kt][2]); r3 = E2(s1[kt][3]);
            }
            lps1 += (r0 + r1) + (r2 + r3);
            uint2 u1 = { pk2bf(r0, r1), pk2bf(r2, r3) };
            __builtin_memcpy(&pb1[kt], &u1, 8);
        }

        __builtin_amdgcn_s_setprio(1);
        #pragma unroll
        for (int kt = 0; kt < 4; ++kt) {
            short8v v0 = *(const short8v*)(Vl + kt * 1024 + oV0);  // dt 0,1
            short8v v1 = *(const short8v*)(Vl + kt * 1024 + oV1);  // dt 2,3
            short4v a0 = __builtin_shufflevector(v0, v0, 0, 1, 2, 3);
            short4v a1 = __builtin_shufflevector(v0, v0, 4, 5, 6, 7);
            short4v a2 = __builtin_shufflevector(v1, v1, 0, 1, 2, 3);
            short4v a3 = __builtin_shufflevector(v1, v1, 4, 5, 6, 7);
            o0[0] = __builtin_amdgcn_mfma_f32_16x16x16bf16_1k(a0, pb0[kt], o0[0], 0, 0, 0);
            o0[1] = __builtin_amdgcn_mfma_f32_16x16x16bf16_1k(a1, pb0[kt], o0[1], 0, 0, 0);
            o0[2] = __builtin_amdgcn_mfma_f32_16x16x16bf16_1k(a2, pb0[kt], o0[2], 0, 0, 0);
            o0[3] = __builtin_amdgcn_mfma_f32_16x16x16bf16_1k(a3, pb0[kt], o0[3], 0, 0, 0);
            o1[0] = __builtin_amdgcn_mfma_f32_16x16x16bf16_1k(a0, pb1[kt], o1[0], 0, 0, 0);
            o1[1] = __builtin_amdgcn_mfma_f32_16x16x16bf16_1k(a1, pb1[kt], o1[1], 0, 0, 0);
            o1[2] = __builtin_amdgcn_mfma_f32_16x16x16bf16_1k(a2, pb1[kt], o1[2], 0, 0, 0);
            o1[3] = __builtin_amdgcn_mfma_f32_16x16x16bf16_1k(a3, pb1[kt], o1[3], 0, 0, 0);
        }
        __builtin_amdgcn_s_setprio(0);
    }

    lps0 += __shfl_xor(lps0, 16);
    lps0 += __shfl_xor(lps0, 32);
    lps1 += __shfl_xor(lps1, 16);
    lps1 += __shfl_xor(lps1, 32);
    const float inv0 = 1.0f / lps0;
    const float inv1 = 1.0f / lps1;
    #pragma unroll
    for (int dt = 0; dt < 4; ++dt) {
        f32x4 r = o0[dt];
        r[0] *= inv0; r[1] *= inv0; r[2] *= inv0; r[3] *= inv0;
        *(f32x4*)(Ob + (size_t)(m0w + cl) * 64 + dt * 16 + quad * 4) = r;
        f32x4 q = o1[dt];
        q[0] *= inv1; q[1] *= inv1; q[2] *= inv1; q[3] *= inv1;
        *(f32x4*)(Ob + (size_t)(m0w + 16 + cl) * 64 + dt * 16 + quad * 4) = q;
    }
}

extern "C" void kernel_launch(void* const* d_in, const int* in_sizes, int n_in,
                              void* d_out, int out_size, void* d_ws, size_t ws_size,
                              hipStream_t stream) {
    const float* x  = (const float*)d_in[0];
    const float* Wq = (const float*)d_in[1];
    const float* Wk = (const float*)d_in[2];
    const float* Wv = (const float*)d_in[3];
    float* out = (float*)d_out;

    // ws: xb 8MB | wc 6MB | QKV natural 24MB | VT3 8MB = 46MB
    unsigned short* xb  = (unsigned short*)d_ws;
    unsigned short* wc  = xb + (size_t)4096 * 1024;
    unsigned short* qkv = wc + (size_t)3 * 1024 * 1024;
    unsigned short* vt  = qkv + (size_t)3 * 4096 * 1024;

    hipLaunchKernelGGL(cast_all, dim3(7168), dim3(256), 0, stream, x, Wq, Wk, Wv, xb, wc);
    hipLaunchKernelGGL(gemm_qkv, dim3(192), dim3(512), 0, stream, xb, wc, qkv);
    hipLaunchKernelGGL(vtrans, dim3(16, 32), dim3(256), 0, stream, qkv + (size_t)2 * 4096 * 1024, vt);
    hipLaunchKernelGGL(attn, dim3(1024), dim3(128), 0, stream, qkv, vt, out);
}

// Round 11
// 143.004 us; speedup vs baseline: 1.0910x; 1.0910x over previous
//
#include <hip/hip_runtime.h>
#include <hip/hip_bf16.h>
#include <stdint.h>

#define AS1 __attribute__((address_space(1)))
#define AS3 __attribute__((address_space(3)))

typedef __bf16 bf16x8 __attribute__((ext_vector_type(8)));
typedef float  f32x4  __attribute__((ext_vector_type(4)));
typedef unsigned short ushort8v __attribute__((ext_vector_type(8)));
typedef unsigned short ushort4v __attribute__((ext_vector_type(4)));
typedef short short8v __attribute__((ext_vector_type(8)));
typedef short short4v __attribute__((ext_vector_type(4)));

__device__ __forceinline__ unsigned short f2bf(float f) {
    unsigned int u = __float_as_uint(f);
    u += 0x7fffu + ((u >> 16) & 1u);           // round-to-nearest-even
    return (unsigned short)(u >> 16);
}
__device__ __forceinline__ unsigned int pk2bf(float a, float b) {
    __hip_bfloat162 h = __float22bfloat162_rn(make_float2(a, b));  // x->low short
    unsigned int u;
    __builtin_memcpy(&u, &h, 4);
    return u;
}
__device__ __forceinline__ void g2lds16(const void* gp, void* lp) {
    __builtin_amdgcn_global_load_lds((AS1 void*)gp, (AS3 void*)lp, 16, 0, 0);
}
#define E2(x) __builtin_amdgcn_exp2f(x)

// ---------------- cast fp32 -> bf16 (x, Wq, Wk, Wv in one launch) -----------
__global__ __launch_bounds__(256) void cast_all(const float* __restrict__ x,
                                                const float* __restrict__ w0,
                                                const float* __restrict__ w1,
                                                const float* __restrict__ w2,
                                                unsigned short* __restrict__ xb,
                                                unsigned short* __restrict__ wc) {
    int id = blockIdx.x;
    const float* s;
    unsigned short* d;
    int base;
    if (id < 4096) { s = x; d = xb; base = id; }
    else {
        int z = (id - 4096) >> 10;
        s = (z == 0) ? w0 : (z == 1) ? w1 : w2;
        d = wc + (size_t)z * 1048576;
        base = (id - 4096) & 1023;
    }
    int i = (base * 256 + threadIdx.x) * 4;
    float4 v = *(const float4*)(s + i);
    ushort4v o = { f2bf(v.x), f2bf(v.y), f2bf(v.z), f2bf(v.w) };
    *(ushort4v*)(d + i) = o;
}

// ---------------- QKV GEMM: R20 fused-N3072, BN=192, 256 blocks -------------
// R18 budget analysis: 192 blocks @ 1 blk/CU (128KB LDS) left 64 CUs IDLE the
// whole gemm — hard 75% ceiling. R20: one fused GEMM C[4096x3072] = X·Wc^T
// (wc is already [Wq;Wk;Wv] contiguous); BM=256, BN=192 -> grid 16x16 = 256
// blocks, 100% CU coverage, per-block work x0.75. Per-wave N=48 (acc[8][3],
// 12 MFMA/phase). B = 3 staging quarters -> 7 granules/K-tile in phases
// {B0,B1 | B2,A0 | A2,A1 | A3}; ledger: entering each tile outstanding =
// {A1,A3} (newest 2 by construction) -> VMW(2) @end-P1 (drains them before
// PHB reads q1/q3) and VMW(2) @end-P4; never 0 in main loop; peel VMW(0)@P1.
// Swizzle identical to R18 (rows ≡ cl mod 8 since 48,16,64,128 ≡ 0 mod 8).
// Epilogue: z = ncol>>10 per 16-lane run (runs never straddle: 1024%16==0);
// Q-scale applied for z==0 only. V (z==2) still lands in natural layout for
// vtrans.
#define VMW(n) asm volatile("s_waitcnt vmcnt(" #n ")" ::: "memory")
#define NOW
#define PHCORE(STG, MFMAS, ENDW) do {                                          \
    STG;                                                                       \
    __builtin_amdgcn_s_barrier();                                              \
    asm volatile("s_waitcnt lgkmcnt(0)" ::: "memory");                         \
    __builtin_amdgcn_sched_barrier(0);                                         \
    __builtin_amdgcn_s_setprio(1);                                             \
    MFMAS;                                                                     \
    __builtin_amdgcn_s_setprio(0);                                             \
    __builtin_amdgcn_sched_barrier(0);                                         \
    ENDW;                                                                      \
    __builtin_amdgcn_s_barrier();                                              \
} while (0)

// PHA: reads 4 A frags (low half) + 3 B frags (kept in bqr for PHB)
#define PHA(S, CUR, STG, ENDW) do {                                            \
    const int kx_ = ((S) * 32 + quad * 8) ^ ((cl & 7) * 8);                    \
    bf16x8 af_[4];                                                             \
    _Pragma("unroll")                                                          \
    for (int m_ = 0; m_ < 4; ++m_)                                             \
        af_[m_] = *(const bf16x8*)&SA[CUR][(rowA0 + m_ * 16) * 64 + kx_];      \
    _Pragma("unroll")                                                          \
    for (int n_ = 0; n_ < 3; ++n_)                                             \
        bqr[n_] = *(const bf16x8*)&SB[CUR][(rowB0 + n_ * 16) * 64 + kx_];      \
    PHCORE(STG,                                                                \
        _Pragma("unroll")                                                      \
        for (int m_ = 0; m_ < 4; ++m_)                                         \
            _Pragma("unroll")                                                  \
            for (int n_ = 0; n_ < 3; ++n_)                                     \
                acc[m_][n_] = __builtin_amdgcn_mfma_f32_16x16x32_bf16(         \
                    af_[m_], bqr[n_], acc[m_][n_], 0, 0, 0);                   \
        , ENDW);                                                               \
} while (0)

// PHB: reads 4 A frags (high half) only, reuses bqr
#define PHB(S, CUR, STG, ENDW) do {                                            \
    const int kx_ = ((S) * 32 + quad * 8) ^ ((cl & 7) * 8);                    \
    bf16x8 af_[4];                                                             \
    _Pragma("unroll")                                                          \
    for (int m_ = 0; m_ < 4; ++m_)                                             \
        af_[m_] = *(const bf16x8*)&SA[CUR][(rowA0 + 64 + m_ * 16) * 64 + kx_]; \
    PHCORE(STG,                                                                \
        _Pragma("unroll")                                                      \
        for (int m_ = 0; m_ < 4; ++m_)                                         \
            _Pragma("unroll")                                                  \
            for (int n_ = 0; n_ < 3; ++n_)                                     \
                acc[4 + m_][n_] = __builtin_amdgcn_mfma_f32_16x16x32_bf16(     \
                    af_[m_], bqr[n_], acc[4 + m_][n_], 0, 0, 0);               \
        , ENDW);                                                               \
} while (0)

__global__ __launch_bounds__(512, 2) void gemm_qkv(const unsigned short* __restrict__ X,
                                                   const unsigned short* __restrict__ W,
                                                   unsigned short* __restrict__ QKV) {
    const int K = 1024;
    const int b = blockIdx.x;                  // 256 blocks
    const int m0 = (b >> 4) * 256;             // 16 m-tiles
    const int n0 = (b & 15) * 192;             // 16 n-tiles over fused N=3072

    const float qs0 = 0.18033688011112042f;    // 0.125*log2(e) for Q (z==0)

    __shared__ unsigned short SA[2][16384];    // [buf][256 rows x 64 k]
    __shared__ unsigned short SB[2][12288];    // [buf][192 rows x 64 k]

    const int t = threadIdx.x;                 // 0..511
    const int w = t >> 6;
    const int l = t & 63;
    const int cl = l & 15;
    const int quad = l >> 4;
    const int rowA0 = (w >> 2) * 128 + cl;
    const int rowB0 = (w & 3) * 48 + cl;

    const int srow8 = t >> 3;                  // row within quarter 0..63
    const int klog = (((t & 7) ^ ((t >> 3) & 7)) * 8);
    const unsigned short* Abase = X + (size_t)(m0 + srow8) * K + klog;
    const unsigned short* Bbase = W + (size_t)(n0 + srow8) * K + klog;
    unsigned short* const sa0 = &SA[0][w * 512];
    unsigned short* const sa1 = &SA[1][w * 512];
    unsigned short* const sb0 = &SB[0][w * 512];
    unsigned short* const sb1 = &SB[1][w * 512];

    f32x4 acc[8][3] = {};
    bf16x8 bqr[3];

#define STGA(nb, q, k0) g2lds16(Abase + (size_t)(q) * 65536 + (k0), ((nb) ? sa1 : sa0) + (q) * 4096)
#define STGB(nb, q, k0) g2lds16(Bbase + (size_t)(q) * 65536 + (k0), ((nb) ? sb1 : sb0) + (q) * 4096)

    // prologue: tile 0 into buf 0 (issue order = steady-state; A1,A3 newest)
    STGB(0, 0, 0); STGB(0, 1, 0); STGB(0, 2, 0);
    STGA(0, 0, 0); STGA(0, 2, 0); STGA(0, 1, 0); STGA(0, 3, 0);
    VMW(2);
    __builtin_amdgcn_s_barrier();

    for (int tt = 0; tt < 15; ++tt) {
        const int cur = tt & 1, nxt = cur ^ 1;
        const int k1 = (tt + 1) * 64;
        PHA(0, cur, { STGB(nxt, 0, k1); STGB(nxt, 1, k1); }, VMW(2));
        PHB(0, cur, { STGB(nxt, 2, k1); STGA(nxt, 0, k1); }, NOW);
        PHA(1, cur, { STGA(nxt, 2, k1); STGA(nxt, 1, k1); }, NOW);
        PHB(1, cur, { STGA(nxt, 3, k1); },                   VMW(2));
    }
    // peeled tile 15 (cur = 1, no staging)
    PHA(0, 1, {}, VMW(0));
    PHB(0, 1, {}, NOW);
    PHA(1, 1, {}, NOW);
    PHB(1, 1, {}, NOW);

#undef STGA
#undef STGB

    #pragma unroll
    for (int mf = 0; mf < 8; ++mf) {
        #pragma unroll
        for (int rr = 0; rr < 4; ++rr) {
            size_t row = (size_t)(m0 + (w >> 2) * 128 + mf * 16 + quad * 4 + rr);
            #pragma unroll
            for (int nf = 0; nf < 3; ++nf) {
                const int nbase = n0 + (w & 3) * 48 + nf * 16;   // 16-aligned
                const int z = nbase >> 10;                        // run-uniform
                const float qs = (z == 0) ? qs0 : 1.0f;
                unsigned short* Cz = QKV + (size_t)z * 4194304;
                Cz[row * 1024 + ((nbase & 1023) + cl)] = f2bf(acc[mf][nf][rr] * qs);
            }
        }
    }
}

// ---------------- V swizzle to VT3 (per bh) ---------------------------------
__global__ __launch_bounds__(256) void vtrans(const unsigned short* __restrict__ Vn,
                                              unsigned short* __restrict__ V3) {
    const int bh = blockIdx.y;
    const int T0 = blockIdx.x * 128;
    __shared__ unsigned short L[128 * 72];
    const int t = threadIdx.x;

    const unsigned short* src = Vn + (size_t)bh * 131072 + (size_t)T0 * 64;
    #pragma unroll
    for (int p = 0; p < 4; ++p) {
        int r = p * 32 + (t >> 3), c = (t & 7) * 8;
        *(ushort8v*)(L + r * 72 + c) = *(const ushort8v*)(src + (size_t)r * 64 + c);
    }
    __syncthreads();
    unsigned short* dst = V3 + (size_t)bh * 131072 + (size_t)(T0 >> 4) * 1024;
    #pragma unroll
    for (int p = 0; p < 2; ++p) {
        int item = p * 256 + t;                 // 512 items: kb(8) x cl(16) x qk(4)
        int kb = item >> 6, cl = (item >> 2) & 15, qk = item & 3;
        ushort8v a, b;
        #pragma unroll
        for (int u = 0; u < 8; ++u) {
            int dt = u >> 2, j = u & 3;
            a[u] = L[(kb * 16 + qk * 4 + j) * 72 + dt * 16 + cl];
            b[u] = L[(kb * 16 + qk * 4 + j) * 72 + (dt + 2) * 16 + cl];
        }
        unsigned short* dp = dst + kb * 1024 + cl * 64 + qk * 16;
        *(ushort8v*)(dp) = a;
        *(ushort8v*)(dp + 8) = b;
    }
}

// ---------------- Flash attention: R14 small-block TLP (reverted) -----------
// R19 post-mortem: 2-wave blocks (q=32/wave) halved LDS reads but dropped to
// 2 waves/SIMD -> latency chains re-exposed (attn 43 -> 48.4, Occ 10.4%).
// R14 (4-wave, 16 q/wave, 4 blk/CU = 4/SIMD w/ independent barrier domains)
// is the measured best; reverted verbatim.
__global__ __launch_bounds__(256, 4) void attn(const unsigned short* __restrict__ QK,
                                               const unsigned short* __restrict__ V3,
                                               float* __restrict__ Out) {
    const int id = blockIdx.x;                         // 1024 blocks
    const int bh = id & 31;                            // 4 bh per XCD (id%8 = XCD)
    const int bb = 31 - (id >> 5);                     // 64-row band, heavy-first
    const int t = threadIdx.x;                         // 0..255
    const int w = t >> 6;                              // wave 0..3
    const int l = t & 63;
    const int cl = l & 15;
    const int quad = l >> 4;
    const int c7 = cl & 7;

    const size_t bhoff = (size_t)bh * 131072;
    const unsigned short* Qb = QK + bhoff;
    const unsigned short* Kb = QK + (size_t)4194304 + bhoff;
    const unsigned short* Vb = V3 + bhoff;
    float* Ob = Out + bhoff;

    __shared__ unsigned short KVs[2][8192];            // per buf: K 4096 | V 4096

    // staging: thread t stages granules t and t+256 of K and of V (R9 maps)
    const int g2 = t + 256;
    const int kO1 = (t >> 3) * 64 + (((t & 7) ^ ((t >> 3) & 7)) * 8);
    const int kO2 = (g2 >> 3) * 64 + (((g2 & 7) ^ ((g2 >> 3) & 7)) * 8);
    const int wg1 = t & 63;
    const int wg2 = g2 & 63;
    const int vO1 = (t >> 6) * 512 + ((wg1 ^ ((wg1 >> 3) & 7)) * 8);
    const int vO2 = (g2 >> 6) * 512 + ((wg2 ^ ((wg2 >> 3) & 7)) * 8);
    const int lB1 = w * 512;                           // shorts (wave-uniform)
    const int lB2 = 2048 + w * 512;

    // read offsets (R9-verified)
    const int oK0 = cl * 64 + (((quad)     ^ c7) * 8);
    const int oK1 = cl * 64 + (((quad + 4) ^ c7) * 8);
    const int oV0 = cl * 64 + (((quad * 2)     ^ c7) * 8);
    const int oV1 = cl * 64 + (((quad * 2 + 1) ^ c7) * 8);

    const int mrel = w * 16 + cl;                      // diag row rel. chunk base
    const int nch = bb + 1;                            // chunks for this band
    const int m0w = bb * 64 + w * 16;

    bf16x8 qf0, qf1;
    {
        const unsigned short* qa = Qb + (size_t)(m0w + cl) * 64 + quad * 8;
        qf0 = *(const bf16x8*)(qa);
        qf1 = *(const bf16x8*)(qa + 32);
    }

    f32x4 o[4] = {};
    float lps = 0.f;

    // stage chunk 0 into buf 0
    {
        unsigned short* s = &KVs[0][0];
        g2lds16(Kb + kO1, s + lB1);
        g2lds16(Kb + kO2, s + lB2);
        g2lds16(Vb + vO1, s + 4096 + lB1);
        g2lds16(Vb + vO2, s + 4096 + lB2);
    }

    for (int c = 0; c < nch; ++c) {
        __syncthreads();                               // buf[c&1] ready
        if (c + 1 < nch) {
            unsigned short* s = &KVs[(c + 1) & 1][0];
            const size_t off = (size_t)(c + 1) * 4096;
            g2lds16(Kb + off + kO1, s + lB1);
            g2lds16(Kb + off + kO2, s + lB2);
            g2lds16(Vb + off + vO1, s + 4096 + lB1);
            g2lds16(Vb + off + vO2, s + 4096 + lB2);
        }
        const unsigned short* Kl = &KVs[c & 1][0];
        const unsigned short* Vl = Kl + 4096;
        const bool masked = (c == bb);

        bf16x8 kf0[4], kf1[4];
        #pragma unroll
        for (int kt = 0; kt < 4; ++kt) {
            kf0[kt] = *(const bf16x8*)(Kl + kt * 1024 + oK0);
            kf1[kt] = *(const bf16x8*)(Kl + kt * 1024 + oK1);
        }
        f32x4 st[4] = {};
        __builtin_amdgcn_s_setprio(1);
        #pragma unroll
        for (int kt = 0; kt < 4; ++kt) {
            st[kt] = __builtin_amdgcn_mfma_f32_16x16x32_bf16(kf0[kt], qf0, st[kt], 0, 0, 0);
            st[kt] = __builtin_amdgcn_mfma_f32_16x16x32_bf16(kf1[kt], qf1, st[kt], 0, 0, 0);
        }
        __builtin_amdgcn_s_setprio(0);

        short4v pb[4];
        #pragma unroll
        for (int kt = 0; kt < 4; ++kt) {
            float p0, p1, p2, p3;
            if (masked) {
                const int lk = kt * 16 + quad * 4;
                p0 = (lk     <= mrel) ? E2(st[kt][0]) : 0.f;
                p1 = (lk + 1 <= mrel) ? E2(st[kt][1]) : 0.f;
                p2 = (lk + 2 <= mrel) ? E2(st[kt][2]) : 0.f;
                p3 = (lk + 3 <= mrel) ? E2(st[kt][3]) : 0.f;
            } else {
                p0 = E2(st[kt][0]);
                p1 = E2(st[kt][1]);
                p2 = E2(st[kt][2]);
                p3 = E2(st[kt][3]);
            }
            lps += (p0 + p1) + (p2 + p3);
            uint2 u = { pk2bf(p0, p1), pk2bf(p2, p3) };
            short4v pv;
            __builtin_memcpy(&pv, &u, 8);
            pb[kt] = pv;
        }

        __builtin_amdgcn_s_setprio(1);
        #pragma unroll
        for (int kt = 0; kt < 4; ++kt) {
            short8v v0 = *(const short8v*)(Vl + kt * 1024 + oV0);  // dt 0,1
            short8v v1 = *(const short8v*)(Vl + kt * 1024 + oV1);  // dt 2,3
            short4v a0 = __builtin_shufflevector(v0, v0, 0, 1, 2, 3);
            short4v a1 = __builtin_shufflevector(v0, v0, 4, 5, 6, 7);
            short4v a2 = __builtin_shufflevector(v1, v1, 0, 1, 2, 3);
            short4v a3 = __builtin_shufflevector(v1, v1, 4, 5, 6, 7);
            o[0] = __builtin_amdgcn_mfma_f32_16x16x16bf16_1k(a0, pb[kt], o[0], 0, 0, 0);
            o[1] = __builtin_amdgcn_mfma_f32_16x16x16bf16_1k(a1, pb[kt], o[1], 0, 0, 0);
            o[2] = __builtin_amdgcn_mfma_f32_16x16x16bf16_1k(a2, pb[kt], o[2], 0, 0, 0);
            o[3] = __builtin_amdgcn_mfma_f32_16x16x16bf16_1k(a3, pb[kt], o[3], 0, 0, 0);
        }
        __builtin_amdgcn_s_setprio(0);
    }

    lps += __shfl_xor(lps, 16);
    lps += __shfl_xor(lps, 32);
    const float inv = 1.0f / lps;
    #pragma unroll
    for (int dt = 0; dt < 4; ++dt) {
        f32x4 r = o[dt];
        r[0] *= inv; r[1] *= inv; r[2] *= inv; r[3] *= inv;
        *(f32x4*)(Ob + (size_t)(m0w + cl) * 64 + dt * 16 + quad * 4) = r;
    }
}

extern "C" void kernel_launch(void* const* d_in, const int* in_sizes, int n_in,
                              void* d_out, int out_size, void* d_ws, size_t ws_size,
                              hipStream_t stream) {
    const float* x  = (const float*)d_in[0];
    const float* Wq = (const float*)d_in[1];
    const float* Wk = (const float*)d_in[2];
    const float* Wv = (const float*)d_in[3];
    float* out = (float*)d_out;

    // ws: xb 8MB | wc 6MB | QKV natural 24MB | VT3 8MB = 46MB
    unsigned short* xb  = (unsigned short*)d_ws;
    unsigned short* wc  = xb + (size_t)4096 * 1024;
    unsigned short* qkv = wc + (size_t)3 * 1024 * 1024;
    unsigned short* vt  = qkv + (size_t)3 * 4096 * 1024;

    hipLaunchKernelGGL(cast_all, dim3(7168), dim3(256), 0, stream, x, Wq, Wk, Wv, xb, wc);
    hipLaunchKernelGGL(gemm_qkv, dim3(256), dim3(512), 0, stream, xb, wc, qkv);
    hipLaunchKernelGGL(vtrans, dim3(16, 32), dim3(256), 0, stream, qkv + (size_t)2 * 4096 * 1024, vt);
    hipLaunchKernelGGL(attn, dim3(1024), dim3(256), 0, stream, qkv, vt, out);
}

// Round 12
// 138.276 us; speedup vs baseline: 1.1283x; 1.0342x over previous
//
#include <hip/hip_runtime.h>
#include <hip/hip_bf16.h>
#include <stdint.h>

#define AS1 __attribute__((address_space(1)))
#define AS3 __attribute__((address_space(3)))

typedef __bf16 bf16x8 __attribute__((ext_vector_type(8)));
typedef float  f32x4  __attribute__((ext_vector_type(4)));
typedef unsigned short ushort8v __attribute__((ext_vector_type(8)));
typedef unsigned short ushort4v __attribute__((ext_vector_type(4)));
typedef short short8v __attribute__((ext_vector_type(8)));
typedef short short4v __attribute__((ext_vector_type(4)));

__device__ __forceinline__ unsigned short f2bf(float f) {
    unsigned int u = __float_as_uint(f);
    u += 0x7fffu + ((u >> 16) & 1u);           // round-to-nearest-even
    return (unsigned short)(u >> 16);
}
__device__ __forceinline__ unsigned int pk2bf(float a, float b) {
    __hip_bfloat162 h = __float22bfloat162_rn(make_float2(a, b));  // x->low short
    unsigned int u;
    __builtin_memcpy(&u, &h, 4);
    return u;
}
__device__ __forceinline__ void g2lds16(const void* gp, void* lp) {
    __builtin_amdgcn_global_load_lds((AS1 void*)gp, (AS3 void*)lp, 16, 0, 0);
}
#define E2(x) __builtin_amdgcn_exp2f(x)

// ---------------- cast fp32 -> bf16 (x, Wq, Wk, Wv in one launch) -----------
__global__ __launch_bounds__(256) void cast_all(const float* __restrict__ x,
                                                const float* __restrict__ w0,
                                                const float* __restrict__ w1,
                                                const float* __restrict__ w2,
                                                unsigned short* __restrict__ xb,
                                                unsigned short* __restrict__ wc) {
    int id = blockIdx.x;
    const float* s;
    unsigned short* d;
    int base;
    if (id < 4096) { s = x; d = xb; base = id; }
    else {
        int z = (id - 4096) >> 10;
        s = (z == 0) ? w0 : (z == 1) ? w1 : w2;
        d = wc + (size_t)z * 1048576;
        base = (id - 4096) & 1023;
    }
    int i = (base * 256 + threadIdx.x) * 4;
    float4 v = *(const float4*)(s + i);
    ushort4v o = { f2bf(v.x), f2bf(v.y), f2bf(v.z), f2bf(v.w) };
    *(ushort4v*)(d + i) = o;
}

// ---------------- QKV GEMM: R21 = R20 + XCD-pinned m-stripes ----------------
// R20 verified (fused N=3072, BN=192, 256 blocks, 100% CU). R21 decode change
// only: xcd = b&7 owns m-tiles {2xcd, 2xcd+1} x all 16 n-tiles -> each 512KB
// X panel fetched by ONE XCD (L3 X traffic 64MB -> 8MB); W streams either
// way. Bijective (8 x 32 = 256). Loop/ledger/swizzle/epilogue untouched.
#define VMW(n) asm volatile("s_waitcnt vmcnt(" #n ")" ::: "memory")
#define NOW
#define PHCORE(STG, MFMAS, ENDW) do {                                          \
    STG;                                                                       \
    __builtin_amdgcn_s_barrier();                                              \
    asm volatile("s_waitcnt lgkmcnt(0)" ::: "memory");                         \
    __builtin_amdgcn_sched_barrier(0);                                         \
    __builtin_amdgcn_s_setprio(1);                                             \
    MFMAS;                                                                     \
    __builtin_amdgcn_s_setprio(0);                                             \
    __builtin_amdgcn_sched_barrier(0);                                         \
    ENDW;                                                                      \
    __builtin_amdgcn_s_barrier();                                              \
} while (0)

// PHA: reads 4 A frags (low half) + 3 B frags (kept in bqr for PHB)
#define PHA(S, CUR, STG, ENDW) do {                                            \
    const int kx_ = ((S) * 32 + quad * 8) ^ ((cl & 7) * 8);                    \
    bf16x8 af_[4];                                                             \
    _Pragma("unroll")                                                          \
    for (int m_ = 0; m_ < 4; ++m_)                                             \
        af_[m_] = *(const bf16x8*)&SA[CUR][(rowA0 + m_ * 16) * 64 + kx_];      \
    _Pragma("unroll")                                                          \
    for (int n_ = 0; n_ < 3; ++n_)                                             \
        bqr[n_] = *(const bf16x8*)&SB[CUR][(rowB0 + n_ * 16) * 64 + kx_];      \
    PHCORE(STG,                                                                \
        _Pragma("unroll")                                                      \
        for (int m_ = 0; m_ < 4; ++m_)                                         \
            _Pragma("unroll")                                                  \
            for (int n_ = 0; n_ < 3; ++n_)                                     \
                acc[m_][n_] = __builtin_amdgcn_mfma_f32_16x16x32_bf16(         \
                    af_[m_], bqr[n_], acc[m_][n_], 0, 0, 0);                   \
        , ENDW);                                                               \
} while (0)

// PHB: reads 4 A frags (high half) only, reuses bqr
#define PHB(S, CUR, STG, ENDW) do {                                            \
    const int kx_ = ((S) * 32 + quad * 8) ^ ((cl & 7) * 8);                    \
    bf16x8 af_[4];                                                             \
    _Pragma("unroll")                                                          \
    for (int m_ = 0; m_ < 4; ++m_)                                             \
        af_[m_] = *(const bf16x8*)&SA[CUR][(rowA0 + 64 + m_ * 16) * 64 + kx_]; \
    PHCORE(STG,                                                                \
        _Pragma("unroll")                                                      \
        for (int m_ = 0; m_ < 4; ++m_)                                         \
            _Pragma("unroll")                                                  \
            for (int n_ = 0; n_ < 3; ++n_)                                     \
                acc[4 + m_][n_] = __builtin_amdgcn_mfma_f32_16x16x32_bf16(     \
                    af_[m_], bqr[n_], acc[4 + m_][n_], 0, 0, 0);               \
        , ENDW);                                                               \
} while (0)

__global__ __launch_bounds__(512, 2) void gemm_qkv(const unsigned short* __restrict__ X,
                                                   const unsigned short* __restrict__ W,
                                                   unsigned short* __restrict__ QKV) {
    const int K = 1024;
    const int b = blockIdx.x;                  // 256 blocks
    const int xcd = b & 7;                     // id%8 = XCD
    const int j = b >> 3;                      // 0..31
    const int m0 = (xcd * 2 + (j >> 4)) * 256; // 2 m-tiles per XCD
    const int n0 = (j & 15) * 192;             // 16 n-tiles over fused N=3072

    const float qs0 = 0.18033688011112042f;    // 0.125*log2(e) for Q (z==0)

    __shared__ unsigned short SA[2][16384];    // [buf][256 rows x 64 k]
    __shared__ unsigned short SB[2][12288];    // [buf][192 rows x 64 k]

    const int t = threadIdx.x;                 // 0..511
    const int w = t >> 6;
    const int l = t & 63;
    const int cl = l & 15;
    const int quad = l >> 4;
    const int rowA0 = (w >> 2) * 128 + cl;
    const int rowB0 = (w & 3) * 48 + cl;

    const int srow8 = t >> 3;                  // row within quarter 0..63
    const int klog = (((t & 7) ^ ((t >> 3) & 7)) * 8);
    const unsigned short* Abase = X + (size_t)(m0 + srow8) * K + klog;
    const unsigned short* Bbase = W + (size_t)(n0 + srow8) * K + klog;
    unsigned short* const sa0 = &SA[0][w * 512];
    unsigned short* const sa1 = &SA[1][w * 512];
    unsigned short* const sb0 = &SB[0][w * 512];
    unsigned short* const sb1 = &SB[1][w * 512];

    f32x4 acc[8][3] = {};
    bf16x8 bqr[3];

#define STGA(nb, q, k0) g2lds16(Abase + (size_t)(q) * 65536 + (k0), ((nb) ? sa1 : sa0) + (q) * 4096)
#define STGB(nb, q, k0) g2lds16(Bbase + (size_t)(q) * 65536 + (k0), ((nb) ? sb1 : sb0) + (q) * 4096)

    // prologue: tile 0 into buf 0 (issue order = steady-state; A1,A3 newest)
    STGB(0, 0, 0); STGB(0, 1, 0); STGB(0, 2, 0);
    STGA(0, 0, 0); STGA(0, 2, 0); STGA(0, 1, 0); STGA(0, 3, 0);
    VMW(2);
    __builtin_amdgcn_s_barrier();

    for (int tt = 0; tt < 15; ++tt) {
        const int cur = tt & 1, nxt = cur ^ 1;
        const int k1 = (tt + 1) * 64;
        PHA(0, cur, { STGB(nxt, 0, k1); STGB(nxt, 1, k1); }, VMW(2));
        PHB(0, cur, { STGB(nxt, 2, k1); STGA(nxt, 0, k1); }, NOW);
        PHA(1, cur, { STGA(nxt, 2, k1); STGA(nxt, 1, k1); }, NOW);
        PHB(1, cur, { STGA(nxt, 3, k1); },                   VMW(2));
    }
    // peeled tile 15 (cur = 1, no staging)
    PHA(0, 1, {}, VMW(0));
    PHB(0, 1, {}, NOW);
    PHA(1, 1, {}, NOW);
    PHB(1, 1, {}, NOW);

#undef STGA
#undef STGB

    #pragma unroll
    for (int mf = 0; mf < 8; ++mf) {
        #pragma unroll
        for (int rr = 0; rr < 4; ++rr) {
            size_t row = (size_t)(m0 + (w >> 2) * 128 + mf * 16 + quad * 4 + rr);
            #pragma unroll
            for (int nf = 0; nf < 3; ++nf) {
                const int nbase = n0 + (w & 3) * 48 + nf * 16;   // 16-aligned
                const int z = nbase >> 10;                        // run-uniform
                const float qs = (z == 0) ? qs0 : 1.0f;
                unsigned short* Cz = QKV + (size_t)z * 4194304;
                Cz[row * 1024 + ((nbase & 1023) + cl)] = f2bf(acc[mf][nf][rr] * qs);
            }
        }
    }
}

// ---------------- V swizzle to VT3 (per bh) ---------------------------------
__global__ __launch_bounds__(256) void vtrans(const unsigned short* __restrict__ Vn,
                                              unsigned short* __restrict__ V3) {
    const int bh = blockIdx.y;
    const int T0 = blockIdx.x * 128;
    __shared__ unsigned short L[128 * 72];
    const int t = threadIdx.x;

    const unsigned short* src = Vn + (size_t)bh * 131072 + (size_t)T0 * 64;
    #pragma unroll
    for (int p = 0; p < 4; ++p) {
        int r = p * 32 + (t >> 3), c = (t & 7) * 8;
        *(ushort8v*)(L + r * 72 + c) = *(const ushort8v*)(src + (size_t)r * 64 + c);
    }
    __syncthreads();
    unsigned short* dst = V3 + (size_t)bh * 131072 + (size_t)(T0 >> 4) * 1024;
    #pragma unroll
    for (int p = 0; p < 2; ++p) {
        int item = p * 256 + t;                 // 512 items: kb(8) x cl(16) x qk(4)
        int kb = item >> 6, cl = (item >> 2) & 15, qk = item & 3;
        ushort8v a, b;
        #pragma unroll
        for (int u = 0; u < 8; ++u) {
            int dt = u >> 2, j = u & 3;
            a[u] = L[(kb * 16 + qk * 4 + j) * 72 + dt * 16 + cl];
            b[u] = L[(kb * 16 + qk * 4 + j) * 72 + (dt + 2) * 16 + cl];
        }
        unsigned short* dp = dst + kb * 1024 + cl * 64 + qk * 16;
        *(ushort8v*)(dp) = a;
        *(ushort8v*)(dp + 8) = b;
    }
}

// ---------------- Flash attention: R21 = R14 + exact per-CU balance ---------
// R14 structure verified best. Defect found by arithmetic: grid = 1024 = CU
// slots exactly (4 blk/CU, no backfill), and bb = 31-(id>>5) gives CU c bands
// {31,23,15,7}-p -> chunk-sums 80 (c<32) .. 52 (c>=224): +-21% imbalance, and
// heavy CUs end at 1-2 resident blocks (R19's exposed-latency regime). R21:
// 4 dispatch strata s = id>>8: bb = {31-pp, pp, 23-pp, 8+pp}[s] -> every CU
// sums to exactly 66 chunks; heavy block dispatched FIRST so the other three
// backfill around it. Bijective over 32 bands x 32 bh. All else unchanged.
__global__ __launch_bounds__(256, 4) void attn(const unsigned short* __restrict__ QK,
                                               const unsigned short* __restrict__ V3,
                                               float* __restrict__ Out) {
    const int id = blockIdx.x;                         // 1024 blocks
    const int g = id & 255;
    const int s4 = id >> 8;                            // stratum 0..3
    const int bh = g & 31;                             // 4 bh per XCD (id%8 = XCD)
    const int pp = g >> 5;                             // 0..7
    const int bb = (s4 == 0) ? (31 - pp)
                 : (s4 == 1) ? pp
                 : (s4 == 2) ? (23 - pp)
                             : (8 + pp);               // 64-row band
    const int t = threadIdx.x;                         // 0..255
    const int w = t >> 6;                              // wave 0..3
    const int l = t & 63;
    const int cl = l & 15;
    const int quad = l >> 4;
    const int c7 = cl & 7;

    const size_t bhoff = (size_t)bh * 131072;
    const unsigned short* Qb = QK + bhoff;
    const unsigned short* Kb = QK + (size_t)4194304 + bhoff;
    const unsigned short* Vb = V3 + bhoff;
    float* Ob = Out + bhoff;

    __shared__ unsigned short KVs[2][8192];            // per buf: K 4096 | V 4096

    // staging: thread t stages granules t and t+256 of K and of V (R9 maps)
    const int g2 = t + 256;
    const int kO1 = (t >> 3) * 64 + (((t & 7) ^ ((t >> 3) & 7)) * 8);
    const int kO2 = (g2 >> 3) * 64 + (((g2 & 7) ^ ((g2 >> 3) & 7)) * 8);
    const int wg1 = t & 63;
    const int wg2 = g2 & 63;
    const int vO1 = (t >> 6) * 512 + ((wg1 ^ ((wg1 >> 3) & 7)) * 8);
    const int vO2 = (g2 >> 6) * 512 + ((wg2 ^ ((wg2 >> 3) & 7)) * 8);
    const int lB1 = w * 512;                           // shorts (wave-uniform)
    const int lB2 = 2048 + w * 512;

    // read offsets (R9-verified)
    const int oK0 = cl * 64 + (((quad)     ^ c7) * 8);
    const int oK1 = cl * 64 + (((quad + 4) ^ c7) * 8);
    const int oV0 = cl * 64 + (((quad * 2)     ^ c7) * 8);
    const int oV1 = cl * 64 + (((quad * 2 + 1) ^ c7) * 8);

    const int mrel = w * 16 + cl;                      // diag row rel. chunk base
    const int nch = bb + 1;                            // chunks for this band
    const int m0w = bb * 64 + w * 16;

    bf16x8 qf0, qf1;
    {
        const unsigned short* qa = Qb + (size_t)(m0w + cl) * 64 + quad * 8;
        qf0 = *(const bf16x8*)(qa);
        qf1 = *(const bf16x8*)(qa + 32);
    }

    f32x4 o[4] = {};
    float lps = 0.f;

    // stage chunk 0 into buf 0
    {
        unsigned short* s = &KVs[0][0];
        g2lds16(Kb + kO1, s + lB1);
        g2lds16(Kb + kO2, s + lB2);
        g2lds16(Vb + vO1, s + 4096 + lB1);
        g2lds16(Vb + vO2, s + 4096 + lB2);
    }

    for (int c = 0; c < nch; ++c) {
        __syncthreads();                               // buf[c&1] ready
        if (c + 1 < nch) {
            unsigned short* s = &KVs[(c + 1) & 1][0];
            const size_t off = (size_t)(c + 1) * 4096;
            g2lds16(Kb + off + kO1, s + lB1);
            g2lds16(Kb + off + kO2, s + lB2);
            g2lds16(Vb + off + vO1, s + 4096 + lB1);
            g2lds16(Vb + off + vO2, s + 4096 + lB2);
        }
        const unsigned short* Kl = &KVs[c & 1][0];
        const unsigned short* Vl = Kl + 4096;
        const bool masked = (c == bb);

        bf16x8 kf0[4], kf1[4];
        #pragma unroll
        for (int kt = 0; kt < 4; ++kt) {
            kf0[kt] = *(const bf16x8*)(Kl + kt * 1024 + oK0);
            kf1[kt] = *(const bf16x8*)(Kl + kt * 1024 + oK1);
        }
        f32x4 st[4] = {};
        __builtin_amdgcn_s_setprio(1);
        #pragma unroll
        for (int kt = 0; kt < 4; ++kt) {
            st[kt] = __builtin_amdgcn_mfma_f32_16x16x32_bf16(kf0[kt], qf0, st[kt], 0, 0, 0);
            st[kt] = __builtin_amdgcn_mfma_f32_16x16x32_bf16(kf1[kt], qf1, st[kt], 0, 0, 0);
        }
        __builtin_amdgcn_s_setprio(0);

        short4v pb[4];
        #pragma unroll
        for (int kt = 0; kt < 4; ++kt) {
            float p0, p1, p2, p3;
            if (masked) {
                const int lk = kt * 16 + quad * 4;
                p0 = (lk     <= mrel) ? E2(st[kt][0]) : 0.f;
                p1 = (lk + 1 <= mrel) ? E2(st[kt][1]) : 0.f;
                p2 = (lk + 2 <= mrel) ? E2(st[kt][2]) : 0.f;
                p3 = (lk + 3 <= mrel) ? E2(st[kt][3]) : 0.f;
            } else {
                p0 = E2(st[kt][0]);
                p1 = E2(st[kt][1]);
                p2 = E2(st[kt][2]);
                p3 = E2(st[kt][3]);
            }
            lps += (p0 + p1) + (p2 + p3);
            uint2 u = { pk2bf(p0, p1), pk2bf(p2, p3) };
            short4v pv;
            __builtin_memcpy(&pv, &u, 8);
            pb[kt] = pv;
        }

        __builtin_amdgcn_s_setprio(1);
        #pragma unroll
        for (int kt = 0; kt < 4; ++kt) {
            short8v v0 = *(const short8v*)(Vl + kt * 1024 + oV0);  // dt 0,1
            short8v v1 = *(const short8v*)(Vl + kt * 1024 + oV1);  // dt 2,3
            short4v a0 = __builtin_shufflevector(v0, v0, 0, 1, 2, 3);
            short4v a1 = __builtin_shufflevector(v0, v0, 4, 5, 6, 7);
            short4v a2 = __builtin_shufflevector(v1, v1, 0, 1, 2, 3);
            short4v a3 = __builtin_shufflevector(v1, v1, 4, 5, 6, 7);
            o[0] = __builtin_amdgcn_mfma_f32_16x16x16bf16_1k(a0, pb[kt], o[0], 0, 0, 0);
            o[1] = __builtin_amdgcn_mfma_f32_16x16x16bf16_1k(a1, pb[kt], o[1], 0, 0, 0);
            o[2] = __builtin_amdgcn_mfma_f32_16x16x16bf16_1k(a2, pb[kt], o[2], 0, 0, 0);
            o[3] = __builtin_amdgcn_mfma_f32_16x16x16bf16_1k(a3, pb[kt], o[3], 0, 0, 0);
        }
        __builtin_amdgcn_s_setprio(0);
    }

    lps += __shfl_xor(lps, 16);
    lps += __shfl_xor(lps, 32);
    const float inv = 1.0f / lps;
    #pragma unroll
    for (int dt = 0; dt < 4; ++dt) {
        f32x4 r = o[dt];
        r[0] *= inv; r[1] *= inv; r[2] *= inv; r[3] *= inv;
        *(f32x4*)(Ob + (size_t)(m0w + cl) * 64 + dt * 16 + quad * 4) = r;
    }
}

extern "C" void kernel_launch(void* const* d_in, const int* in_sizes, int n_in,
                              void* d_out, int out_size, void* d_ws, size_t ws_size,
                              hipStream_t stream) {
    const float* x  = (const float*)d_in[0];
    const float* Wq = (const float*)d_in[1];
    const float* Wk = (const float*)d_in[2];
    const float* Wv = (const float*)d_in[3];
    float* out = (float*)d_out;

    // ws: xb 8MB | wc 6MB | QKV natural 24MB | VT3 8MB = 46MB
    unsigned short* xb  = (unsigned short*)d_ws;
    unsigned short* wc  = xb + (size_t)4096 * 1024;
    unsigned short* qkv = wc + (size_t)3 * 1024 * 1024;
    unsigned short* vt  = qkv + (size_t)3 * 4096 * 1024;

    hipLaunchKernelGGL(cast_all, dim3(7168), dim3(256), 0, stream, x, Wq, Wk, Wv, xb, wc);
    hipLaunchKernelGGL(gemm_qkv, dim3(256), dim3(512), 0, stream, xb, wc, qkv);
    hipLaunchKernelGGL(vtrans, dim3(16, 32), dim3(256), 0, stream, qkv + (size_t)2 * 4096 * 1024, vt);
    hipLaunchKernelGGL(attn, dim3(1024), dim3(256), 0, stream, qkv, vt, out);
}